// Round 1
// baseline (2846.240 us; speedup 1.0000x reference)
//
#include <hip/hip_runtime.h>
#include <hip/hip_bf16.h>

typedef unsigned short u16;
typedef __attribute__((ext_vector_type(8))) short bhalf8;
typedef __attribute__((ext_vector_type(4))) float f32x4;

__device__ inline f32x4 mfma_bf16(bhalf8 a, bhalf8 b, f32x4 c) {
    return __builtin_amdgcn_mfma_f32_16x16x32_bf16(a, b, c, 0, 0, 0);
}

__device__ inline u16 f2bf(float f) {
    union { float f; unsigned u; } v; v.f = f;
    unsigned u = v.u;
    return (u16)((u + 0x7fff + ((u >> 16) & 1)) >> 16);
}

// ---------------- prologue kernels ----------------

// out[mat][c][r] = bf16(in[mat][r][c])   (weight transpose+convert)
__global__ __launch_bounds__(256) void k_wtrans(const float* in, u16* out, int rows, int cols) {
    int mat = blockIdx.y;
    size_t rc = (size_t)rows * cols;
    size_t idx = (size_t)blockIdx.x * 256 + threadIdx.x;
    if (idx >= rc) return;
    int r = (int)(idx / cols), c = (int)(idx % cols);
    out[mat * rc + (size_t)c * rows + r] = f2bf(in[mat * rc + idx]);
}

// xp = bf16(x + pos_embed)  (x: [2,4096,256], pos: [4096,256])
__global__ __launch_bounds__(256) void k_addpos(const float* x, const float* pos, u16* xp) {
    size_t idx = (size_t)blockIdx.x * 256 + threadIdx.x;   // < 2*4096*256
    size_t p = idx & ((size_t)4096 * 256 - 1);
    xp[idx] = f2bf(x[idx] + pos[p]);
}

// h = y (fp32), hb = bf16(y)
__global__ __launch_bounds__(256) void k_inith(const float* y, float* h, u16* hb) {
    size_t idx = (size_t)blockIdx.x * 256 + threadIdx.x;
    float v = y[idx];
    h[idx] = v; hb[idx] = f2bf(v);
}

// v [B*Sk,256] -> vt [B,4,64,Sk]
__global__ __launch_bounds__(256) void k_vtrans(const u16* v, u16* vt, int Sk) {
    size_t idx = (size_t)blockIdx.x * 256 + threadIdx.x;   // < 2*Sk*256
    int c = (int)(idx & 255);
    size_t sidx = idx >> 8;
    int s = (int)(sidx % Sk), b = (int)(sidx / Sk);
    int hh = c >> 6, d = c & 63;
    vt[(((size_t)(b * 4 + hh) * 64 + d) * Sk) + s] = v[idx];
}

// ---------------- GEMM ----------------
// C[M,N] = A[M,K](bf16) @ W[K,N] + bias, weights pre-transposed Wt[N,K].
// MODE 0: out bf16, scale applied when z==0 (for Q pre-scaling)
// MODE 1: out bf16 with tanh-GELU
// MODE 2: out fp32 (pre-LN residual branch)
template <int MODE>
__global__ __launch_bounds__(256) void k_gemm(const u16* A, const u16* Wt0, const float* bias0,
                                              void* out0, int M, int N, int K,
                                              long wz, long bz, long oz, float scale0) {
    int z = blockIdx.z;
    const u16* Wt = Wt0 + (size_t)z * wz;
    const float* bias = bias0 + (size_t)z * bz;
    int wave = threadIdx.x >> 6, lane = threadIdx.x & 63;
    int l16 = lane & 15, quad = lane >> 4;
    int row0 = blockIdx.x * 64 + wave * 16;
    int col0 = blockIdx.y * 64;

    f32x4 acc[4];
    for (int nt = 0; nt < 4; nt++) acc[nt] = (f32x4){0.f, 0.f, 0.f, 0.f};

    const u16* arow = A + (size_t)(row0 + l16) * K + quad * 8;
    for (int k0 = 0; k0 < K; k0 += 32) {
        bhalf8 a = *(const bhalf8*)(arow + k0);
        #pragma unroll
        for (int nt = 0; nt < 4; nt++) {
            const u16* wrow = Wt + (size_t)(col0 + nt * 16 + l16) * K + k0 + quad * 8;
            bhalf8 b = *(const bhalf8*)wrow;
            acc[nt] = mfma_bf16(a, b, acc[nt]);
        }
    }

    float scl = (MODE == 0) ? ((z == 0) ? scale0 : 1.f) : 1.f;
    #pragma unroll
    for (int nt = 0; nt < 4; nt++) {
        int col = col0 + nt * 16 + l16;
        float bs = bias[col];
        #pragma unroll
        for (int r = 0; r < 4; r++) {
            int row = row0 + quad * 4 + r;
            float v = acc[nt][r] + bs;
            if (MODE == 0) {
                v *= scl;
                ((u16*)out0)[(size_t)z * oz + (size_t)row * N + col] = f2bf(v);
            } else if (MODE == 1) {
                float g = 0.5f * v * (1.f + tanhf(0.7978845608028654f * (v + 0.044715f * v * v * v)));
                ((u16*)out0)[(size_t)row * N + col] = f2bf(g);
            } else {
                ((float*)out0)[(size_t)row * N + col] = v;
            }
        }
    }
}

// ---------------- flash attention ----------------
// q,k: [B*S,256] bf16 (q pre-scaled), vt: [B,4,64,Sk] bf16, ctx out bf16 [B*Sq,256]
__global__ __launch_bounds__(256) void k_attn(const u16* q, const u16* k, const u16* vt,
                                              u16* ctx, int Sq, int Sk) {
    int b = blockIdx.y >> 2, h = blockIdx.y & 3;
    int wave = threadIdx.x >> 6, lane = threadIdx.x & 63;
    int l16 = lane & 15, quad = lane >> 4;
    int qrow0 = blockIdx.x * 64 + wave * 16;

    __shared__ u16 plds[4][16][32];

    const u16* qrow = q + ((size_t)(b * Sq) + qrow0 + l16) * 256 + h * 64;
    bhalf8 aq0 = *(const bhalf8*)(qrow + quad * 8);
    bhalf8 aq1 = *(const bhalf8*)(qrow + 32 + quad * 8);

    float m_r[4] = {-1e30f, -1e30f, -1e30f, -1e30f};
    float l_r[4] = {0.f, 0.f, 0.f, 0.f};
    f32x4 o[4];
    for (int nt = 0; nt < 4; nt++) o[nt] = (f32x4){0.f, 0.f, 0.f, 0.f};

    const u16* vbase = vt + (size_t)((b * 4 + h) * 64) * Sk;

    for (int kk = 0; kk < Sk; kk += 32) {
        f32x4 s[2];
        #pragma unroll
        for (int jt = 0; jt < 2; jt++) {
            const u16* krow = k + ((size_t)(b * Sk) + kk + jt * 16 + l16) * 256 + h * 64;
            bhalf8 bk0 = *(const bhalf8*)(krow + quad * 8);
            bhalf8 bk1 = *(const bhalf8*)(krow + 32 + quad * 8);
            f32x4 acc = (f32x4){0.f, 0.f, 0.f, 0.f};
            acc = mfma_bf16(aq0, bk0, acc);
            acc = mfma_bf16(aq1, bk1, acc);
            s[jt] = acc;
        }
        float p0[4], p1[4];
        #pragma unroll
        for (int r = 0; r < 4; r++) {
            float mx = fmaxf(s[0][r], s[1][r]);
            for (int off = 8; off >= 1; off >>= 1) mx = fmaxf(mx, __shfl_xor(mx, off, 16));
            float mnew = fmaxf(m_r[r], mx);
            float alpha = __expf(m_r[r] - mnew);
            p0[r] = __expf(s[0][r] - mnew);
            p1[r] = __expf(s[1][r] - mnew);
            float ps = p0[r] + p1[r];
            for (int off = 8; off >= 1; off >>= 1) ps += __shfl_xor(ps, off, 16);
            l_r[r] = l_r[r] * alpha + ps;
            m_r[r] = mnew;
            o[0][r] *= alpha; o[1][r] *= alpha; o[2][r] *= alpha; o[3][r] *= alpha;
        }
        __syncthreads();   // previous iteration's reads of plds are done
        #pragma unroll
        for (int r = 0; r < 4; r++) {
            plds[wave][quad * 4 + r][l16]      = f2bf(p0[r]);
            plds[wave][quad * 4 + r][16 + l16] = f2bf(p1[r]);
        }
        __syncthreads();   // writes visible
        bhalf8 ap = *(const bhalf8*)&plds[wave][l16][quad * 8];
        #pragma unroll
        for (int nt = 0; nt < 4; nt++) {
            const u16* vrow = vbase + (size_t)(nt * 16 + l16) * Sk + kk + quad * 8;
            bhalf8 bv = *(const bhalf8*)vrow;
            o[nt] = mfma_bf16(ap, bv, o[nt]);
        }
    }

    #pragma unroll
    for (int nt = 0; nt < 4; nt++) {
        #pragma unroll
        for (int r = 0; r < 4; r++) {
            float val = o[nt][r] / l_r[r];
            ctx[((size_t)(b * Sq) + qrow0 + quad * 4 + r) * 256 + h * 64 + nt * 16 + l16] = f2bf(val);
        }
    }
}

// ---------------- LayerNorm(h + add) ----------------
__global__ __launch_bounds__(256) void k_ln(const float* hin, const float* add,
                                            const float* g, const float* bta,
                                            float* hout, u16* hb) {
    int row = blockIdx.x, t = threadIdx.x;
    size_t base = (size_t)row * 256 + t;
    float x = hin[base] + add[base];
    float s = x, s2 = x * x;
    for (int off = 32; off >= 1; off >>= 1) {
        s += __shfl_xor(s, off, 64);
        s2 += __shfl_xor(s2, off, 64);
    }
    __shared__ float red[8];
    int wave = t >> 6, lane = t & 63;
    if (lane == 0) { red[wave] = s; red[4 + wave] = s2; }
    __syncthreads();
    if (t == 0) {
        float ts = red[0] + red[1] + red[2] + red[3];
        float tq = red[4] + red[5] + red[6] + red[7];
        float mu = ts * (1.f / 256.f);
        float var = tq * (1.f / 256.f) - mu * mu;
        red[0] = mu; red[1] = rsqrtf(var + 1e-12f);
    }
    __syncthreads();
    float mu = red[0], rs = red[1];
    float y = (x - mu) * rs * g[t] + bta[t];
    hout[base] = y;
    hb[base] = f2bf(y);
}

// ---------------- host ----------------
extern "C" void kernel_launch(void* const* d_in, const int* in_sizes, int n_in,
                              void* d_out, int out_size, void* d_ws, size_t ws_size,
                              hipStream_t stream) {
    const float* x        = (const float*)d_in[0];
    const float* y        = (const float*)d_in[1];
    const float* pos      = (const float*)d_in[2];
    const float* sqkv_w   = (const float*)d_in[3];
    const float* sqkv_b   = (const float*)d_in[4];
    const float* so_w     = (const float*)d_in[5];
    const float* so_b     = (const float*)d_in[6];
    const float* cqkv_w   = (const float*)d_in[7];
    const float* cqkv_b   = (const float*)d_in[8];
    const float* co_w     = (const float*)d_in[9];
    const float* co_b     = (const float*)d_in[10];
    const float* ffn_w1   = (const float*)d_in[11];
    const float* ffn_b1   = (const float*)d_in[12];
    const float* ffn_w2   = (const float*)d_in[13];
    const float* ffn_b2   = (const float*)d_in[14];
    const float* ln_g     = (const float*)d_in[15];
    const float* ln_b     = (const float*)d_in[16];

    char* w = (char*)d_ws;
    auto alloc = [&](size_t bytes) { char* p = w; w += (bytes + 255) & ~(size_t)255; return p; };

    u16* wt_sqkv = (u16*)alloc(18ull * 65536 * 2);
    u16* wt_so   = (u16*)alloc(6ull  * 65536 * 2);
    u16* wt_cqkv = (u16*)alloc(18ull * 65536 * 2);
    u16* wt_co   = (u16*)alloc(6ull  * 65536 * 2);
    u16* wt_f1   = (u16*)alloc(6ull  * 262144 * 2);
    u16* wt_f2   = (u16*)alloc(6ull  * 262144 * 2);
    u16* xp      = (u16*)alloc(2097152ull * 2);
    float* hf    = (float*)alloc(1048576ull * 4);
    u16* hb      = (u16*)alloc(1048576ull * 2);
    u16* qkv     = (u16*)alloc(3ull * 1048576 * 2);
    u16* kv      = (u16*)alloc(2ull * 2097152 * 2);
    u16* vt      = (u16*)alloc(2097152ull * 2);
    u16* ctx     = (u16*)alloc(1048576ull * 2);
    float* aout  = (float*)alloc(1048576ull * 4);
    u16* f1      = (u16*)alloc(4194304ull * 2);

    // prologue: weight transposes + encoder input + h init
    k_wtrans<<<dim3(256, 18), 256, 0, stream>>>(sqkv_w, wt_sqkv, 256, 256);
    k_wtrans<<<dim3(256, 6),  256, 0, stream>>>(so_w,   wt_so,   256, 256);
    k_wtrans<<<dim3(256, 18), 256, 0, stream>>>(cqkv_w, wt_cqkv, 256, 256);
    k_wtrans<<<dim3(256, 6),  256, 0, stream>>>(co_w,   wt_co,   256, 256);
    k_wtrans<<<dim3(1024, 6), 256, 0, stream>>>(ffn_w1, wt_f1,   256, 1024);
    k_wtrans<<<dim3(1024, 6), 256, 0, stream>>>(ffn_w2, wt_f2,   1024, 256);
    k_addpos<<<dim3(8192), 256, 0, stream>>>(x, pos, xp);
    k_inith<<<dim3(4096), 256, 0, stream>>>(y, hf, hb);

    const float qscale = 0.125f;  // 1/sqrt(64)

    for (int i = 0; i < 6; i++) {
        // ---- self attention ----
        k_gemm<0><<<dim3(64, 4, 3), 256, 0, stream>>>(hb, wt_sqkv + (size_t)i * 3 * 65536,
            sqkv_b + i * 768, qkv, 4096, 256, 256, 65536, 256, 1048576, qscale);
        k_vtrans<<<dim3(4096), 256, 0, stream>>>(qkv + 2ull * 1048576, vt, 2048);
        k_attn<<<dim3(32, 8), 256, 0, stream>>>(qkv, qkv + 1048576, vt, ctx, 2048, 2048);
        k_gemm<2><<<dim3(64, 4, 1), 256, 0, stream>>>(ctx, wt_so + (size_t)i * 65536,
            so_b + i * 256, aout, 4096, 256, 256, 0, 0, 0, 1.f);
        k_ln<<<dim3(4096), 256, 0, stream>>>(hf, aout, ln_g + (i * 3 + 0) * 256,
            ln_b + (i * 3 + 0) * 256, hf, hb);

        // ---- cross attention ----
        k_gemm<0><<<dim3(64, 4, 1), 256, 0, stream>>>(hb, wt_cqkv + (size_t)i * 3 * 65536,
            cqkv_b + i * 768, qkv, 4096, 256, 256, 0, 0, 0, qscale);
        k_gemm<0><<<dim3(128, 4, 2), 256, 0, stream>>>(xp, wt_cqkv + (size_t)i * 3 * 65536 + 65536,
            cqkv_b + i * 768 + 256, kv, 8192, 256, 256, 65536, 256, 2097152, 1.f);
        k_vtrans<<<dim3(8192), 256, 0, stream>>>(kv + 2097152, vt, 4096);
        k_attn<<<dim3(32, 8), 256, 0, stream>>>(qkv, kv, vt, ctx, 2048, 4096);
        k_gemm<2><<<dim3(64, 4, 1), 256, 0, stream>>>(ctx, wt_co + (size_t)i * 65536,
            co_b + i * 256, aout, 4096, 256, 256, 0, 0, 0, 1.f);
        k_ln<<<dim3(4096), 256, 0, stream>>>(hf, aout, ln_g + (i * 3 + 1) * 256,
            ln_b + (i * 3 + 1) * 256, hf, hb);

        // ---- FFN ----
        k_gemm<1><<<dim3(64, 16, 1), 256, 0, stream>>>(hb, wt_f1 + (size_t)i * 262144,
            ffn_b1 + i * 1024, f1, 4096, 1024, 256, 0, 0, 0, 1.f);
        k_gemm<2><<<dim3(64, 4, 1), 256, 0, stream>>>(f1, wt_f2 + (size_t)i * 262144,
            ffn_b2 + i * 256, aout, 4096, 256, 1024, 0, 0, 0, 1.f);
        float* dst = (i == 5) ? (float*)d_out : hf;
        k_ln<<<dim3(4096), 256, 0, stream>>>(hf, aout, ln_g + (i * 3 + 2) * 256,
            ln_b + (i * 3 + 2) * 256, dst, hb);
    }
}

// Round 2
// 2009.000 us; speedup vs baseline: 1.4167x; 1.4167x over previous
//
#include <hip/hip_runtime.h>
#include <hip/hip_bf16.h>

typedef unsigned short u16;
typedef __attribute__((ext_vector_type(8))) short bhalf8;
typedef __attribute__((ext_vector_type(4))) float f32x4;

__device__ inline f32x4 mfma_bf16(bhalf8 a, bhalf8 b, f32x4 c) {
    return __builtin_amdgcn_mfma_f32_16x16x32_bf16(a, b, c, 0, 0, 0);
}

__device__ inline u16 f2bf(float f) {
    union { float f; unsigned u; } v; v.f = f;
    unsigned u = v.u;
    return (u16)((u + 0x7fff + ((u >> 16) & 1)) >> 16);
}

// ---------------- prologue kernels ----------------

// out[mat][c][r] = bf16(in[mat][r][c])   (weight transpose+convert)
__global__ __launch_bounds__(256) void k_wtrans(const float* in, u16* out, int rows, int cols) {
    int mat = blockIdx.y;
    size_t rc = (size_t)rows * cols;
    size_t idx = (size_t)blockIdx.x * 256 + threadIdx.x;
    if (idx >= rc) return;
    int r = (int)(idx / cols), c = (int)(idx % cols);
    out[mat * rc + (size_t)c * rows + r] = f2bf(in[mat * rc + idx]);
}

// xp = bf16(x + pos_embed)  (x: [2,4096,256], pos: [4096,256])
__global__ __launch_bounds__(256) void k_addpos(const float* x, const float* pos, u16* xp) {
    size_t idx = (size_t)blockIdx.x * 256 + threadIdx.x;
    size_t p = idx & ((size_t)4096 * 256 - 1);
    xp[idx] = f2bf(x[idx] + pos[p]);
}

// h = y (fp32), hb = bf16(y)
__global__ __launch_bounds__(256) void k_inith(const float* y, float* h, u16* hb) {
    size_t idx = (size_t)blockIdx.x * 256 + threadIdx.x;
    float v = y[idx];
    h[idx] = v; hb[idx] = f2bf(v);
}

// ---------------- GEMM ----------------
// C[M,N] = A[M,K](bf16) @ W[K,N] + bias, weights pre-transposed Wt[N,K].
// Per-wave tile: 16 rows x 32 cols (2 nt). Grid (M/64, N/32, Z).
// MODE 0: bf16 out; z==0 scaled by scale0; z==vz redirected to V-transposed layout
// MODE 1: bf16 out with tanh-GELU
// MODE 2: fp32 out
template <int MODE>
__global__ __launch_bounds__(256) void k_gemm(const u16* A, const u16* Wt0, const float* bias0,
                                              void* out0, u16* vt_out, int M, int N, int K,
                                              long wz, long bz, long oz, float scale0,
                                              int vz, int Skv) {
    int z = blockIdx.z;
    const u16* Wt = Wt0 + (size_t)z * wz;
    const float* bias = bias0 + (size_t)z * bz;
    int wave = threadIdx.x >> 6, lane = threadIdx.x & 63;
    int l16 = lane & 15, quad = lane >> 4;
    int row0 = blockIdx.x * 64 + wave * 16;
    int col0 = blockIdx.y * 32;

    f32x4 acc0 = (f32x4){0.f, 0.f, 0.f, 0.f};
    f32x4 acc1 = (f32x4){0.f, 0.f, 0.f, 0.f};
    const u16* arow = A + (size_t)(row0 + l16) * K + quad * 8;
    const u16* w0 = Wt + (size_t)(col0 + l16) * K + quad * 8;
    const u16* w1 = w0 + (size_t)16 * K;
    for (int k0 = 0; k0 < K; k0 += 32) {
        bhalf8 a = *(const bhalf8*)(arow + k0);
        acc0 = mfma_bf16(a, *(const bhalf8*)(w0 + k0), acc0);
        acc1 = mfma_bf16(a, *(const bhalf8*)(w1 + k0), acc1);
    }

    f32x4 accs[2] = {acc0, acc1};
    #pragma unroll
    for (int nt = 0; nt < 2; nt++) {
        int col = col0 + nt * 16 + l16;
        float bs = bias[col];
        if (MODE == 0 && z == vz) {
            int row = row0 + quad * 4;
            int bb = row / Skv;
            int s = row - bb * Skv;
            int hh = col >> 6, d = col & 63;
            ushort4 pk;
            pk.x = f2bf(accs[nt][0] + bs);
            pk.y = f2bf(accs[nt][1] + bs);
            pk.z = f2bf(accs[nt][2] + bs);
            pk.w = f2bf(accs[nt][3] + bs);
            *(ushort4*)(vt_out + ((size_t)((bb * 4 + hh) * 64 + d) * Skv + s)) = pk;
        } else if (MODE == 0) {
            float scl = (z == 0) ? scale0 : 1.f;
            u16* op = (u16*)out0 + (size_t)z * oz;
            #pragma unroll
            for (int r = 0; r < 4; r++)
                op[(size_t)(row0 + quad * 4 + r) * N + col] = f2bf((accs[nt][r] + bs) * scl);
        } else if (MODE == 1) {
            #pragma unroll
            for (int r = 0; r < 4; r++) {
                float v = accs[nt][r] + bs;
                float g = 0.5f * v * (1.f + tanhf(0.7978845608028654f * (v + 0.044715f * v * v * v)));
                ((u16*)out0)[(size_t)(row0 + quad * 4 + r) * N + col] = f2bf(g);
            }
        } else {
            #pragma unroll
            for (int r = 0; r < 4; r++)
                ((float*)out0)[(size_t)(row0 + quad * 4 + r) * N + col] = accs[nt][r] + bs;
        }
    }
}

// ---------------- flash attention (S^T formulation, Sk split across 4 waves) ----------------
// q,k: [B*S,256] bf16 (q pre-scaled), vt: [B,4,64,Sk] bf16, ctx out bf16 [B*Sq,256]
// grid: (Sq/16, B*4); block 256. Each block = one 16-row q-tile; wave w handles keys
// [w*Sk/4, (w+1)*Sk/4), partials merged through LDS at the end.
__global__ __launch_bounds__(256, 4) void k_attn(const u16* q, const u16* k, const u16* vt,
                                                 u16* ctx, int Sq, int Sk) {
    int b = blockIdx.y >> 2, h = blockIdx.y & 3;
    int wave = threadIdx.x >> 6, lane = threadIdx.x & 63;
    int l16 = lane & 15, quad = lane >> 4;
    int q0 = blockIdx.x * 16;
    int Skw = Sk >> 2;
    int kbeg = wave * Skw;

    __shared__ f32x4 lo[4][4][4][16];   // [wave][nt][quad][l16]
    __shared__ float lm[4][16];
    __shared__ float ll[4][16];

    // Q as B-operand: lane l16 = q row, k = quad*8+j over d
    const u16* qrow = q + ((size_t)(b * Sq) + q0 + l16) * 256 + h * 64;
    bhalf8 bq0 = *(const bhalf8*)(qrow + quad * 8);
    bhalf8 bq1 = *(const bhalf8*)(qrow + 32 + quad * 8);

    float m = -1e30f, l = 0.f;
    f32x4 o[4];
    #pragma unroll
    for (int nt = 0; nt < 4; nt++) o[nt] = (f32x4){0.f, 0.f, 0.f, 0.f};

    const u16* kbase = k + (size_t)(b * Sk) * 256 + h * 64;
    const u16* vbase = vt + (size_t)((b * 4 + h) * 64) * Sk;
    int srcA = l16 + ((quad & 1) << 5);
    int srcB = srcA + 16;
    bool hi = quad >= 2;

    for (int kk = kbeg; kk < kbeg + Skw; kk += 32) {
        // S^T tiles: s0 = keys kk..kk+15, s1 = keys kk+16..kk+31 (rows), q cols
        const u16* kr0 = kbase + (size_t)(kk + l16) * 256;
        const u16* kr1 = kr0 + (size_t)16 * 256;
        f32x4 s0 = (f32x4){0.f, 0.f, 0.f, 0.f};
        f32x4 s1 = (f32x4){0.f, 0.f, 0.f, 0.f};
        s0 = mfma_bf16(*(const bhalf8*)(kr0 + quad * 8), bq0, s0);
        s0 = mfma_bf16(*(const bhalf8*)(kr0 + 32 + quad * 8), bq1, s0);
        s1 = mfma_bf16(*(const bhalf8*)(kr1 + quad * 8), bq0, s1);
        s1 = mfma_bf16(*(const bhalf8*)(kr1 + 32 + quad * 8), bq1, s1);

        // online softmax per q (= per l16 lane column), reduce across quads
        float mx = fmaxf(fmaxf(fmaxf(s0[0], s0[1]), fmaxf(s0[2], s0[3])),
                         fmaxf(fmaxf(s1[0], s1[1]), fmaxf(s1[2], s1[3])));
        mx = fmaxf(mx, __shfl_xor(mx, 16, 64));
        mx = fmaxf(mx, __shfl_xor(mx, 32, 64));
        float mnew = fmaxf(m, mx);
        float alpha = __expf(m - mnew);
        float p0[4], p1[4], ps = 0.f;
        #pragma unroll
        for (int r = 0; r < 4; r++) {
            p0[r] = __expf(s0[r] - mnew);
            p1[r] = __expf(s1[r] - mnew);
            ps += p0[r] + p1[r];
        }
        ps += __shfl_xor(ps, 16, 64);
        ps += __shfl_xor(ps, 32, 64);
        l = l * alpha + ps;
        m = mnew;
        #pragma unroll
        for (int nt = 0; nt < 4; nt++) o[nt] *= alpha;

        // P^T (C-layout) -> B-operand fragment via cross-quad shuffles
        union { bhalf8 v; u16 e[8]; } bp;
        #pragma unroll
        for (int r = 0; r < 4; r++) {
            unsigned pk2 = ((unsigned)f2bf(p1[r]) << 16) | (unsigned)f2bf(p0[r]);
            unsigned xA = (unsigned)__shfl((int)pk2, srcA, 64);
            unsigned xB = (unsigned)__shfl((int)pk2, srcB, 64);
            bp.e[r]     = hi ? (u16)(xA >> 16) : (u16)(xA & 0xffffu);
            bp.e[4 + r] = hi ? (u16)(xB >> 16) : (u16)(xB & 0xffffu);
        }

        // O^T += Vt-tile (A) @ P^T (B)
        #pragma unroll
        for (int nt = 0; nt < 4; nt++) {
            const u16* vr = vbase + (size_t)(nt * 16 + l16) * Sk + kk + quad * 8;
            o[nt] = mfma_bf16(*(const bhalf8*)vr, bp.v, o[nt]);
        }
    }

    // merge the 4 waves' partials
    #pragma unroll
    for (int nt = 0; nt < 4; nt++) lo[wave][nt][quad][l16] = o[nt];
    if (quad == 0) { lm[wave][l16] = m; ll[wave][l16] = l; }
    __syncthreads();

    float M2 = fmaxf(fmaxf(lm[0][l16], lm[1][l16]), fmaxf(lm[2][l16], lm[3][l16]));
    float sc0 = __expf(lm[0][l16] - M2), sc1 = __expf(lm[1][l16] - M2);
    float sc2 = __expf(lm[2][l16] - M2), sc3 = __expf(lm[3][l16] - M2);
    float L = sc0 * ll[0][l16] + sc1 * ll[1][l16] + sc2 * ll[2][l16] + sc3 * ll[3][l16];
    float invL = 1.f / L;
    f32x4 of = lo[0][wave][quad][l16] * sc0 + lo[1][wave][quad][l16] * sc1 +
               lo[2][wave][quad][l16] * sc2 + lo[3][wave][quad][l16] * sc3;
    ushort4 pkv;
    pkv.x = f2bf(of[0] * invL);
    pkv.y = f2bf(of[1] * invL);
    pkv.z = f2bf(of[2] * invL);
    pkv.w = f2bf(of[3] * invL);
    *(ushort4*)(ctx + ((size_t)(b * Sq) + q0 + l16) * 256 + h * 64 + wave * 16 + quad * 4) = pkv;
}

// ---------------- LayerNorm(h + add) ----------------
__global__ __launch_bounds__(256) void k_ln(const float* hin, const float* add,
                                            const float* g, const float* bta,
                                            float* hout, u16* hb) {
    int row = blockIdx.x, t = threadIdx.x;
    size_t base = (size_t)row * 256 + t;
    float x = hin[base] + add[base];
    float s = x, s2 = x * x;
    for (int off = 32; off >= 1; off >>= 1) {
        s += __shfl_xor(s, off, 64);
        s2 += __shfl_xor(s2, off, 64);
    }
    __shared__ float red[8];
    int wave = t >> 6, lane = t & 63;
    if (lane == 0) { red[wave] = s; red[4 + wave] = s2; }
    __syncthreads();
    if (t == 0) {
        float ts = red[0] + red[1] + red[2] + red[3];
        float tq = red[4] + red[5] + red[6] + red[7];
        float mu = ts * (1.f / 256.f);
        float var = tq * (1.f / 256.f) - mu * mu;
        red[0] = mu; red[1] = rsqrtf(var + 1e-12f);
    }
    __syncthreads();
    float mu = red[0], rs = red[1];
    float y = (x - mu) * rs * g[t] + bta[t];
    hout[base] = y;
    hb[base] = f2bf(y);
}

// ---------------- host ----------------
extern "C" void kernel_launch(void* const* d_in, const int* in_sizes, int n_in,
                              void* d_out, int out_size, void* d_ws, size_t ws_size,
                              hipStream_t stream) {
    const float* x        = (const float*)d_in[0];
    const float* y        = (const float*)d_in[1];
    const float* pos      = (const float*)d_in[2];
    const float* sqkv_w   = (const float*)d_in[3];
    const float* sqkv_b   = (const float*)d_in[4];
    const float* so_w     = (const float*)d_in[5];
    const float* so_b     = (const float*)d_in[6];
    const float* cqkv_w   = (const float*)d_in[7];
    const float* cqkv_b   = (const float*)d_in[8];
    const float* co_w     = (const float*)d_in[9];
    const float* co_b     = (const float*)d_in[10];
    const float* ffn_w1   = (const float*)d_in[11];
    const float* ffn_b1   = (const float*)d_in[12];
    const float* ffn_w2   = (const float*)d_in[13];
    const float* ffn_b2   = (const float*)d_in[14];
    const float* ln_g     = (const float*)d_in[15];
    const float* ln_b     = (const float*)d_in[16];

    char* w = (char*)d_ws;
    auto alloc = [&](size_t bytes) { char* p = w; w += (bytes + 255) & ~(size_t)255; return p; };

    u16* wt_sqkv = (u16*)alloc(18ull * 65536 * 2);
    u16* wt_so   = (u16*)alloc(6ull  * 65536 * 2);
    u16* wt_cqkv = (u16*)alloc(18ull * 65536 * 2);
    u16* wt_co   = (u16*)alloc(6ull  * 65536 * 2);
    u16* wt_f1   = (u16*)alloc(6ull  * 262144 * 2);
    u16* wt_f2   = (u16*)alloc(6ull  * 262144 * 2);
    u16* xp      = (u16*)alloc(2097152ull * 2);
    float* hf    = (float*)alloc(1048576ull * 4);
    u16* hb      = (u16*)alloc(1048576ull * 2);
    u16* qkv     = (u16*)alloc(2ull * 1048576 * 2);   // Q, K row-major
    u16* kv      = (u16*)alloc(2097152ull * 2);        // cross K row-major
    u16* vt      = (u16*)alloc(2097152ull * 2);        // V transposed [B,4,64,Sk]
    u16* ctx     = (u16*)alloc(1048576ull * 2);
    float* aout  = (float*)alloc(1048576ull * 4);
    u16* f1      = (u16*)alloc(4194304ull * 2);

    // prologue: weight transposes + encoder input + h init
    k_wtrans<<<dim3(256, 18), 256, 0, stream>>>(sqkv_w, wt_sqkv, 256, 256);
    k_wtrans<<<dim3(256, 6),  256, 0, stream>>>(so_w,   wt_so,   256, 256);
    k_wtrans<<<dim3(256, 18), 256, 0, stream>>>(cqkv_w, wt_cqkv, 256, 256);
    k_wtrans<<<dim3(256, 6),  256, 0, stream>>>(co_w,   wt_co,   256, 256);
    k_wtrans<<<dim3(1024, 6), 256, 0, stream>>>(ffn_w1, wt_f1,   256, 1024);
    k_wtrans<<<dim3(1024, 6), 256, 0, stream>>>(ffn_w2, wt_f2,   1024, 256);
    k_addpos<<<dim3(8192), 256, 0, stream>>>(x, pos, xp);
    k_inith<<<dim3(4096), 256, 0, stream>>>(y, hf, hb);

    const float qscale = 0.125f;  // 1/sqrt(64)

    for (int i = 0; i < 6; i++) {
        // ---- self attention: QKV (V direct to vt layout), attn, o-proj, LN ----
        k_gemm<0><<<dim3(64, 8, 3), 256, 0, stream>>>(hb, wt_sqkv + (size_t)i * 3 * 65536,
            sqkv_b + i * 768, qkv, vt, 4096, 256, 256, 65536, 256, 1048576, qscale, 2, 2048);
        k_attn<<<dim3(128, 8), 256, 0, stream>>>(qkv, qkv + 1048576, vt, ctx, 2048, 2048);
        k_gemm<2><<<dim3(64, 8, 1), 256, 0, stream>>>(ctx, wt_so + (size_t)i * 65536,
            so_b + i * 256, aout, nullptr, 4096, 256, 256, 0, 0, 0, 1.f, -1, 0);
        k_ln<<<dim3(4096), 256, 0, stream>>>(hf, aout, ln_g + (i * 3 + 0) * 256,
            ln_b + (i * 3 + 0) * 256, hf, hb);

        // ---- cross attention ----
        k_gemm<0><<<dim3(64, 8, 1), 256, 0, stream>>>(hb, wt_cqkv + (size_t)i * 3 * 65536,
            cqkv_b + i * 768, qkv, nullptr, 4096, 256, 256, 0, 0, 0, qscale, -1, 0);
        k_gemm<0><<<dim3(128, 8, 2), 256, 0, stream>>>(xp, wt_cqkv + (size_t)i * 3 * 65536 + 65536,
            cqkv_b + i * 768 + 256, kv, vt, 8192, 256, 256, 65536, 256, 0, 1.f, 1, 4096);
        k_attn<<<dim3(128, 8), 256, 0, stream>>>(qkv, kv, vt, ctx, 2048, 4096);
        k_gemm<2><<<dim3(64, 8, 1), 256, 0, stream>>>(ctx, wt_co + (size_t)i * 65536,
            co_b + i * 256, aout, nullptr, 4096, 256, 256, 0, 0, 0, 1.f, -1, 0);
        k_ln<<<dim3(4096), 256, 0, stream>>>(hf, aout, ln_g + (i * 3 + 1) * 256,
            ln_b + (i * 3 + 1) * 256, hf, hb);

        // ---- FFN ----
        k_gemm<1><<<dim3(64, 32, 1), 256, 0, stream>>>(hb, wt_f1 + (size_t)i * 262144,
            ffn_b1 + i * 1024, f1, nullptr, 4096, 1024, 256, 0, 0, 0, 1.f, -1, 0);
        k_gemm<2><<<dim3(64, 8, 1), 256, 0, stream>>>(f1, wt_f2 + (size_t)i * 262144,
            ffn_b2 + i * 256, aout, nullptr, 4096, 256, 1024, 0, 0, 0, 1.f, -1, 0);
        float* dst = (i == 5) ? (float*)d_out : hf;
        k_ln<<<dim3(4096), 256, 0, stream>>>(hf, aout, ln_g + (i * 3 + 2) * 256,
            ln_b + (i * 3 + 2) * 256, dst, hb);
    }
}